// Round 12
// baseline (917.455 us; speedup 1.0000x reference)
//
#include <hip/hip_runtime.h>
#include <math.h>

#define NSRC 10000
#define NEDGE 320000
#define EDIM 236
#define TOPN 6

typedef __attribute__((ext_vector_type(8))) short short8;
typedef __attribute__((ext_vector_type(4))) float floatx4;

typedef __attribute__((address_space(3))) void lds_void_t;
typedef __attribute__((address_space(1))) const void gmem_void_t;

// async 16B/lane global->LDS: lane l writes lds_base + l*16
__device__ __forceinline__ void g2lds16(const void* g, void* l) {
  __builtin_amdgcn_global_load_lds((gmem_void_t*)g, (lds_void_t*)l, 16, 0, 0);
}

// ---------------------------------------------------------------- bf16 split
__device__ __forceinline__ unsigned short bf16_rne(float x) {
  union { float f; unsigned int u; } c; c.f = x;
  unsigned int r = (c.u + 0x7FFFu + ((c.u >> 16) & 1u)) >> 16;
  return (unsigned short)r;
}
__device__ __forceinline__ float bf16_to_f(unsigned short h) {
  union { unsigned int u; float f; } c; c.u = ((unsigned int)h) << 16;
  return c.f;
}
__device__ __forceinline__ void split_f32(float x, unsigned short& h, unsigned short& l) {
  h = bf16_rne(x);
  l = bf16_rne(x - bf16_to_f(h));
}

// fast split of 8 floats into hi/lo bf16 via v_cvt_pk_bf16_f32 (RNE, bit-identical
// to bf16_rne for normal values)
__device__ __forceinline__ void split8(const float* av, short8& h8, short8& l8) {
  union { short8 s; unsigned int u[4]; } H, L;
#pragma unroll
  for (int p = 0; p < 4; ++p) {
    float x0 = av[2 * p], x1 = av[2 * p + 1];
    unsigned int hp;
    asm("v_cvt_pk_bf16_f32 %0, %1, %2" : "=v"(hp) : "v"(x0), "v"(x1));
    union { unsigned int u; float f; } f0, f1;
    f0.u = hp << 16;
    f1.u = hp & 0xFFFF0000u;
    float l0 = x0 - f0.f, l1 = x1 - f1.f;
    unsigned int lp;
    asm("v_cvt_pk_bf16_f32 %0, %1, %2" : "=v"(lp) : "v"(l0), "v"(l1));
    H.u[p] = hp; L.u[p] = lp;
  }
  h8 = H.s; l8 = L.s;
}

// ---------------------------------------------------------------- top-k utils
struct KV { float v; int i; };

__device__ __forceinline__ bool kv_better(const KV a, const KV b) {
  return (a.v > b.v) || (a.v == b.v && a.i < b.i);
}

__device__ __forceinline__ void kv_merge(KV d[TOPN], const KV o[TOPN]) {
  KV r[TOPN];
  int ia = 0, ib = 0;
#pragma unroll
  for (int q = 0; q < TOPN; ++q) {
    bool takeA;
    if (ia >= TOPN) takeA = false;
    else if (ib >= TOPN) takeA = true;
    else takeA = kv_better(d[ia], o[ib]);
    r[q] = takeA ? d[ia] : o[ib];
    if (takeA) ia++; else ib++;
  }
#pragma unroll
  for (int q = 0; q < TOPN; ++q) d[q] = r[q];
}

__global__ void k_sentinel(float* __restrict__ out) {
  if (threadIdx.x == 0) out[0] = 1.0e9f;
}

// ---------------------------------------------------------------- mega prep
__global__ __launch_bounds__(256)
void k_prep_all(const float* __restrict__ cew, const float* __restrict__ ceb,
                const float* __restrict__ cw1, const float* __restrict__ cw2,
                const float* __restrict__ l1w, const float* __restrict__ l2w,
                const float* __restrict__ psw, const float* __restrict__ l2b,
                const float* __restrict__ psb, const float* __restrict__ ptb,
                const float* __restrict__ ptw,
                float* __restrict__ w1cat, float* __restrict__ wew1cat,
                float* __restrict__ bprime, float* __restrict__ m1,
                unsigned short* __restrict__ Bh, unsigned short* __restrict__ Bl,
                float* __restrict__ bcat, float* __restrict__ biascat,
                float* __restrict__ statsT, int* __restrict__ counts) {
  const int b = blockIdx.x;
  const int tid = threadIdx.x;
  if (b < 708) {                      // wew1cat[k][i*128+j] = sum_m We_i[k][m]*W1_i[m][j]
    if (tid >= 128) return;
    int i = b / EDIM;
    int k = b - i * EDIM;
    const float* we = cew + ((size_t)i * EDIM + k) * 128;
    const float* w1 = cw1 + (size_t)i * 16384;
    float acc = 0.f;
    for (int m = 0; m < 128; ++m) acc = fmaf(we[m], w1[m * 128 + tid], acc);
    wew1cat[k * 384 + i * 128 + tid] = acc;
  } else if (b < 1092) {              // m1[(i*128+r)][j] = sum_c W2_i[r][c]*lin1_W[(i*128+c)][j]
    if (tid >= 128) return;
    int bb = b - 708;
    int i = bb >> 7;
    int r = bb & 127;
    const float* w2 = cw2 + (size_t)i * 16384 + r * 128;
    float acc = 0.f;
    for (int c = 0; c < 128; ++c) acc = fmaf(w2[c], l1w[((size_t)i * 128 + c) * 128 + tid], acc);
    m1[bb * 128 + tid] = acc;
  } else if (b < 1284) {              // w1cat transpose-copy
    int gid = (b - 1092) * 256 + tid;
    if (gid >= 3 * 128 * 128) return;
    int i = gid >> 14;
    int m = (gid >> 7) & 127;
    int j = gid & 127;
    w1cat[m * 384 + i * 128 + j] = cw1[gid];
  } else if (b < 1287) {              // bprime[i*128+j] = sum_m be_i[m]*W1_i[m][j]
    if (tid >= 128) return;
    int i = b - 1284;
    const float* be = ceb + i * 128;
    const float* w1 = cw1 + (size_t)i * 16384;
    float acc = 0.f;
    for (int m = 0; m < 128; ++m) acc = fmaf(be[m], w1[m * 128 + tid], acc);
    bprime[i * 128 + tid] = acc;
  } else if (b < 1415) {              // B split: ptw [236][128] -> Bh/Bl [128][256]
    int n = b - 1287;
    float v = (tid < EDIM) ? ptw[(size_t)tid * 128 + n] : 0.f;
    unsigned short h, l;
    split_f32(v, h, l);
    Bh[n * 256 + tid] = h;
    Bl[n * 256 + tid] = l;
  } else if (b < 1543) {              // bcat [128][256] = [l2w | l2w@psw]; biascat
    if (tid >= 128) return;
    int k = b - 1415;
    bcat[k * 256 + tid] = l2w[k * 128 + tid];
    float acc = 0.f;
    for (int c = 0; c < 128; ++c) acc = fmaf(l2w[k * 128 + c], psw[c * 128 + tid], acc);
    bcat[k * 256 + 128 + tid] = acc;
    if (k == 0) {
      biascat[tid] = l2b[tid];
      float bb = 0.f;
      for (int c = 0; c < 128; ++c) bb = fmaf(l2b[c], psw[c * 128 + tid], bb);
      biascat[128 + tid] = bb + psb[tid] + ptb[tid];
    }
  } else if (b < 1551) {              // zero statsT(1536)+statsP(512)
    int i = (b - 1543) * 256 + tid;
    if (i < 2048) statsT[i] = 0.f;
  } else {                            // zero counts(10000)
    int i = (b - 1551) * 256 + tid;
    if (i < NSRC) counts[i] = 0;
  }
}

// ---------------------------------------------------------------- CSR build
__global__ __launch_bounds__(256) void k_hist(const int* __restrict__ src,
                                              int* __restrict__ counts) {
  int e = blockIdx.x * 256 + threadIdx.x;
  if (e < NEDGE) atomicAdd(&counts[src[e]], 1);
}

__global__ __launch_bounds__(256) void k_scan(const int* __restrict__ counts,
                                              int* __restrict__ offsets,
                                              int* __restrict__ cursor) {
  __shared__ int part[256];
  const int t = threadIdx.x;
  const int base = t * 40;
  int s = 0;
  for (int k = 0; k < 40; ++k) {
    int i = base + k;
    if (i < NSRC) s += counts[i];
  }
  part[t] = s;
  __syncthreads();
  for (int off = 1; off < 256; off <<= 1) {
    int v = (t >= off) ? part[t - off] : 0;
    __syncthreads();
    part[t] += v;
    __syncthreads();
  }
  int run = (t == 0) ? 0 : part[t - 1];
  for (int k = 0; k < 40; ++k) {
    int i = base + k;
    if (i < NSRC) {
      offsets[i] = run;
      cursor[i] = run;
      run += counts[i];
    }
  }
  if (t == 255) offsets[NSRC] = run;
}

__global__ __launch_bounds__(256) void k_scatter(const int* __restrict__ src,
                                                 int* __restrict__ cursor,
                                                 int* __restrict__ elist) {
  int e = blockIdx.x * 256 + threadIdx.x;
  if (e < NEDGE) {
    int p = atomicAdd(&cursor[src[e]], 1);
    elist[p] = e;
  }
}

// agg[row][d] = sum over row's edges of relu(pf[e][d]).
// Wave-per-edge float4 gather: rows are 944 B = 59 x 16 B (16B-aligned), so lane l
// reads float4 #l of the row (l<59) -- one wave-wide contiguous read per edge,
// 4 edges in flight per block, 2-deep unrolled. Per-thread loads 32 scalar -> 8
// float4. Cross-wave reduce via LDS; agg row written as 59 coalesced float4.
__global__ __launch_bounds__(256) void k_gather(const float* __restrict__ pf,
                                                const int* __restrict__ offsets,
                                                const int* __restrict__ elist,
                                                float* __restrict__ agg) {
  const int row = blockIdx.x;
  const int tid = threadIdx.x;
  const int wave = tid >> 6;
  const int lane = tid & 63;
  __shared__ int sid[64];
  __shared__ float4 red[3][64];
  const int beg = offsets[row];
  const int end = offsets[row + 1];
  float4 a = make_float4(0.f, 0.f, 0.f, 0.f);
  float4 b2 = make_float4(0.f, 0.f, 0.f, 0.f);
  for (int b = beg; b < end; b += 64) {
    const int cnt = min(64, end - b);
    __syncthreads();
    if (tid < cnt) sid[tid] = elist[b + tid];
    __syncthreads();
    if (lane < 59) {
      int e = wave;
      for (; e + 4 < cnt; e += 8) {
        const float* p0 = pf + (size_t)sid[e] * EDIM;
        const float* p1 = pf + (size_t)sid[e + 4] * EDIM;
        const float4 v0 = *(const float4*)(p0 + lane * 4);
        const float4 v1 = *(const float4*)(p1 + lane * 4);
        a.x += fmaxf(v0.x, 0.f); a.y += fmaxf(v0.y, 0.f);
        a.z += fmaxf(v0.z, 0.f); a.w += fmaxf(v0.w, 0.f);
        b2.x += fmaxf(v1.x, 0.f); b2.y += fmaxf(v1.y, 0.f);
        b2.z += fmaxf(v1.z, 0.f); b2.w += fmaxf(v1.w, 0.f);
      }
      if (e < cnt) {
        const float* p0 = pf + (size_t)sid[e] * EDIM;
        const float4 v0 = *(const float4*)(p0 + lane * 4);
        a.x += fmaxf(v0.x, 0.f); a.y += fmaxf(v0.y, 0.f);
        a.z += fmaxf(v0.z, 0.f); a.w += fmaxf(v0.w, 0.f);
      }
    }
  }
  a.x += b2.x; a.y += b2.y; a.z += b2.z; a.w += b2.w;
  __syncthreads();
  if (wave > 0 && lane < 59) red[wave - 1][lane] = a;
  __syncthreads();
  if (wave == 0 && lane < 59) {
    const float4 r0 = red[0][lane];
    const float4 r1 = red[1][lane];
    const float4 r2 = red[2][lane];
    a.x = (a.x + r0.x) + (r1.x + r2.x);
    a.y = (a.y + r0.y) + (r1.y + r2.y);
    a.z = (a.z + r0.z) + (r1.z + r2.z);
    a.w = (a.w + r0.w) + (r1.w + r2.w);
    *(float4*)(agg + (size_t)row * EDIM + lane * 4) = a;
  }
}

// ---------------------------------------------------------------- merged T GEMM (64x64 tiles)
// T[10000,384] = paths_srcs@w1cat + agg@wew1cat + bprime; col sum/sumsq -> statsT
__global__ __launch_bounds__(256)
void k_gemmT(const float* __restrict__ A1, const float* __restrict__ B1,
             const float* __restrict__ A2, const float* __restrict__ B2,
             const float* __restrict__ bias, float* __restrict__ C,
             float* __restrict__ colsum, float* __restrict__ colsumsq) {
  __shared__ float As[8][64];
  __shared__ float Bs[8][64];
  __shared__ float red[16][64];
  const int tid = threadIdx.x;
  const int tx = tid & 15;
  const int ty = tid >> 4;
  const int bm = blockIdx.x * 64;
  const int bn = blockIdx.y * 64;
  const int N = 384;

  float acc[4][4];
#pragma unroll
  for (int i = 0; i < 4; ++i)
#pragma unroll
    for (int j = 0; j < 4; ++j) acc[i][j] = 0.f;

  const int ar = tid & 63;            // A stage row
  const int ac = (tid >> 6) << 1;     // A stage k-pair
  const int bkr = tid >> 5;           // B stage k row
  const int bc = (tid & 31) << 1;     // B stage col pair

#pragma unroll 1
  for (int seg = 0; seg < 2; ++seg) {
    const float* A = seg ? A2 : A1;
    const float* B = seg ? B2 : B1;
    const int K = seg ? EDIM : 128;
    for (int k0 = 0; k0 < K; k0 += 8) {
      {
        float2 v = make_float2(0.f, 0.f);
        int row = bm + ar;
        int k = k0 + ac;
        if (row < NSRC) {
          if (k + 2 <= K) v = *(const float2*)(A + (size_t)row * K + k);
          else if (k < K) v.x = A[(size_t)row * K + k];
        }
        As[ac][ar] = v.x;
        As[ac + 1][ar] = v.y;
      }
      {
        float2 v = make_float2(0.f, 0.f);
        int kk = k0 + bkr;
        if (kk < K) v = *(const float2*)(B + (size_t)kk * N + bn + bc);
        Bs[bkr][bc] = v.x;
        Bs[bkr][bc + 1] = v.y;
      }
      __syncthreads();
#pragma unroll
      for (int kk = 0; kk < 8; ++kk) {
        const float4 a0 = *(const float4*)&As[kk][ty * 4];
        const float4 b0 = *(const float4*)&Bs[kk][tx * 4];
        const float av[4] = {a0.x, a0.y, a0.z, a0.w};
        const float bv[4] = {b0.x, b0.y, b0.z, b0.w};
#pragma unroll
        for (int i = 0; i < 4; ++i)
#pragma unroll
          for (int j = 0; j < 4; ++j) acc[i][j] = fmaf(av[i], bv[j], acc[i][j]);
      }
      __syncthreads();
    }
  }

  const int nb = bn + tx * 4;
  float colS[4], colQ[4];
#pragma unroll
  for (int j = 0; j < 4; ++j) { colS[j] = 0.f; colQ[j] = 0.f; }
#pragma unroll
  for (int i = 0; i < 4; ++i) {
    int m = bm + ty * 4 + i;
    if (m < NSRC) {
      float outv[4];
#pragma unroll
      for (int j = 0; j < 4; ++j) outv[j] = acc[i][j] + bias[nb + j];
      *(float4*)(C + (size_t)m * N + nb) = make_float4(outv[0], outv[1], outv[2], outv[3]);
#pragma unroll
      for (int j = 0; j < 4; ++j) { colS[j] += outv[j]; colQ[j] += outv[j] * outv[j]; }
    }
  }
  *(float4*)&red[ty][tx * 4] = make_float4(colS[0], colS[1], colS[2], colS[3]);
  __syncthreads();
  if (tid < 64) {
    float s = 0.f;
#pragma unroll
    for (int t = 0; t < 16; ++t) s += red[t][tid];
    atomicAdd(colsum + bn + tid, s);
  }
  __syncthreads();
  *(float4*)&red[ty][tx * 4] = make_float4(colQ[0], colQ[1], colQ[2], colQ[3]);
  __syncthreads();
  if (tid < 64) {
    float s = 0.f;
#pragma unroll
    for (int t = 0; t < 16; ++t) s += red[t][tid];
    atomicAdd(colsumsq + bn + tid, s);
  }
}

// ---------------------------------------------------------------- fp32 GEMM (node, 64x64 tiles)
// ATR: 0=none, 2=BN from raw sums + relu on A-load
// EPI: 2=relu(acc+bias); 5=dual-out: col<128 -> C, col>=128 -> C2, both stride 128
template <int ATR, int EPI>
__global__ __launch_bounds__(256)
void gemm_k(const float* __restrict__ A, const float* __restrict__ B,
            float* __restrict__ C, int M, int K, int N,
            const float* __restrict__ bn_g, const float* __restrict__ bn_b,
            const float* __restrict__ rawS, const float* __restrict__ rawQ,
            const float* __restrict__ bias, float* __restrict__ C2) {
  __shared__ float As[8][64];
  __shared__ float Bs[8][64];
  const int tid = threadIdx.x;
  const int tx = tid & 15;
  const int ty = tid >> 4;
  const int bm = blockIdx.x * 64;
  const int bn = blockIdx.y * 64;

  float acc[4][4];
#pragma unroll
  for (int i = 0; i < 4; ++i)
#pragma unroll
    for (int j = 0; j < 4; ++j) acc[i][j] = 0.f;

  const int ar = tid & 63;
  const int ac = (tid >> 6) << 1;
  const int bkr = tid >> 5;
  const int bc = (tid & 31) << 1;

  for (int k0 = 0; k0 < K; k0 += 8) {
    {
      float2 v = make_float2(0.f, 0.f);
      int row = bm + ar;
      int k = k0 + ac;
      if (row < M) {
        if (k + 2 <= K) v = *(const float2*)(A + (size_t)row * K + k);
        else if (k < K) v.x = A[(size_t)row * K + k];
      }
      if constexpr (ATR == 2) {
        float vv[2] = {v.x, v.y};
#pragma unroll
        for (int q = 0; q < 2; ++q) {
          int kk = k0 + ac + q;
          if (kk < K) {
            float mean = rawS[kk] * (1.0f / NSRC);
            float var = rawQ[kk] * (1.0f / NSRC) - mean * mean;
            float rstd = rsqrtf(var + 1e-5f);
            vv[q] = fmaxf(fmaf(bn_g[kk] * rstd, vv[q] - mean, bn_b[kk]), 0.f);
          } else {
            vv[q] = 0.f;
          }
        }
        v = make_float2(vv[0], vv[1]);
      }
      As[ac][ar] = v.x;
      As[ac + 1][ar] = v.y;
    }
    {
      float2 v = make_float2(0.f, 0.f);
      int kk = k0 + bkr;
      if (kk < K) v = *(const float2*)(B + (size_t)kk * N + bn + bc);
      Bs[bkr][bc] = v.x;
      Bs[bkr][bc + 1] = v.y;
    }
    __syncthreads();
#pragma unroll
    for (int kk = 0; kk < 8; ++kk) {
      const float4 a0 = *(const float4*)&As[kk][ty * 4];
      const float4 b0 = *(const float4*)&Bs[kk][tx * 4];
      const float av[4] = {a0.x, a0.y, a0.z, a0.w};
      const float bv[4] = {b0.x, b0.y, b0.z, b0.w};
#pragma unroll
      for (int i = 0; i < 4; ++i)
#pragma unroll
        for (int j = 0; j < 4; ++j) acc[i][j] = fmaf(av[i], bv[j], acc[i][j]);
    }
    __syncthreads();
  }

  const int nb = bn + tx * 4;
#pragma unroll
  for (int i = 0; i < 4; ++i) {
    int m = bm + ty * 4 + i;
    if (m < M) {
      float outv[4];
#pragma unroll
      for (int j = 0; j < 4; ++j) {
        outv[j] = acc[i][j] + bias[nb + j];
        if constexpr (EPI == 2) outv[j] = fmaxf(outv[j], 0.f);
      }
      float* crow;
      if constexpr (EPI == 5) {
        crow = (nb < 128) ? (C + (size_t)m * 128 + nb) : (C2 + (size_t)m * 128 + (nb - 128));
      } else {
        crow = C + (size_t)m * N + nb;
      }
      *(float4*)crow = make_float4(outv[0], outv[1], outv[2], outv[3]);
    }
  }
}

// ---------------------------------------------------------------- big GEMM: split-bf16 MFMA
// hpath[320000,128] = path_feats @ pe_tgt_W + pre_src[srcids[m]]; col sum/sumsq.
// Fragment-ordered double-buffered LDS staged via global_load_lds (async, 4 instr/
// wave/chunk, conflict-free lane-linear ds_read_b128). One barrier per chunk; next
// chunk's B-stage + A-loads issued right after the barrier so they complete under
// the MFMA cluster. A split via v_cvt_pk_bf16_f32 (bit-identical RNE).
// NOTE: this simple __syncthreads structure measured 168 us; three attempts at
// finer-grained pipelining (reg-dbuf, no-LDS-direct-L2, counted-vmcnt+raw-barrier)
// all measured SLOWER (208-276 us). Do not re-add schedule surgery here.
__global__ __launch_bounds__(256)
void k_hgemm(const float* __restrict__ A, const unsigned short* __restrict__ Bh,
             const unsigned short* __restrict__ Bl, const int* __restrict__ srcids,
             const float* __restrict__ pre_src, float* __restrict__ hpath,
             float* __restrict__ colsum, float* __restrict__ colsumsq) {
  // BF[buf][h/l][nt][lane*8 shorts] : each lane's fragment at base + lane*16B
  __shared__ __align__(16) unsigned short BF[2][2][8][512];
  __shared__ float redS[4][128];
  __shared__ float redQ[4][128];

  const int tid = threadIdx.x;
  const int wave = tid >> 6;
  const int lane = tid & 63;
  const int am = lane & 15;
  const int aq = lane >> 4;
  const int bm = blockIdx.x * 128;

  floatx4 acc[2][8];
#pragma unroll
  for (int mt = 0; mt < 2; ++mt)
#pragma unroll
    for (int nt = 0; nt < 8; ++nt) acc[mt][nt] = (floatx4){0.f, 0.f, 0.f, 0.f};

  const float* a0p = A + (size_t)(bm + wave * 32 + am) * EDIM;   // 16B-aligned (944=59*16)
  const float* a1p = a0p + 16 * EDIM;

  // staging: wave w owns nt = {2w, 2w+1}; per-lane src = fragment (nt, lane)
  const int nt0 = wave * 2, nt1 = nt0 + 1;
  const unsigned short* sH0 = Bh + (size_t)(nt0 * 16 + am) * 256 + aq * 8;
  const unsigned short* sH1 = Bh + (size_t)(nt1 * 16 + am) * 256 + aq * 8;
  const unsigned short* sL0 = Bl + (size_t)(nt0 * 16 + am) * 256 + aq * 8;
  const unsigned short* sL1 = Bl + (size_t)(nt1 * 16 + am) * 256 + aq * 8;

  auto stage = [&](int c, int buf) {
    g2lds16(sH0 + c * 32, &BF[buf][0][nt0][0]);
    g2lds16(sH1 + c * 32, &BF[buf][0][nt1][0]);
    g2lds16(sL0 + c * 32, &BF[buf][1][nt0][0]);
    g2lds16(sL1 + c * 32, &BF[buf][1][nt1][0]);
  };

  float pA0[8], pA1[8];
  auto loadA = [&](int c) {
    const int kA = c * 32 + aq * 8;
    if (kA + 8 <= EDIM) {
      float4 x = *(const float4*)(a0p + kA);
      float4 y = *(const float4*)(a0p + kA + 4);
      pA0[0] = x.x; pA0[1] = x.y; pA0[2] = x.z; pA0[3] = x.w;
      pA0[4] = y.x; pA0[5] = y.y; pA0[6] = y.z; pA0[7] = y.w;
      x = *(const float4*)(a1p + kA);
      y = *(const float4*)(a1p + kA + 4);
      pA1[0] = x.x; pA1[1] = x.y; pA1[2] = x.z; pA1[3] = x.w;
      pA1[4] = y.x; pA1[5] = y.y; pA1[6] = y.z; pA1[7] = y.w;
    } else {
#pragma unroll
      for (int q = 0; q < 8; ++q) {
        int k = kA + q;
        pA0[q] = (k < EDIM) ? a0p[k] : 0.f;
        pA1[q] = (k < EDIM) ? a1p[k] : 0.f;
      }
    }
  };

  stage(0, 0);
  loadA(0);
#pragma unroll 1
  for (int c = 0; c < 8; ++c) {
    // split current A (covers in-flight loads with VALU)
    short8 ah0, al0, ah1, al1;
    split8(pA0, ah0, al0);
    split8(pA1, ah1, al1);
    __syncthreads();                 // drains vmcnt: BF[c&1] ready for all waves
    if (c < 7) {
      stage(c + 1, (c + 1) & 1);     // async B for next chunk (other buffer)
      loadA(c + 1);                  // A loads land during MFMA below
    }
    const int buf = c & 1;
#pragma unroll
    for (int nt = 0; nt < 8; ++nt) {
      const short8 bh = *(const short8*)&BF[buf][0][nt][lane * 8];
      const short8 bl = *(const short8*)&BF[buf][1][nt][lane * 8];
      acc[0][nt] = __builtin_amdgcn_mfma_f32_16x16x32_bf16(ah0, bl, acc[0][nt], 0, 0, 0);
      acc[1][nt] = __builtin_amdgcn_mfma_f32_16x16x32_bf16(ah1, bl, acc[1][nt], 0, 0, 0);
      acc[0][nt] = __builtin_amdgcn_mfma_f32_16x16x32_bf16(al0, bh, acc[0][nt], 0, 0, 0);
      acc[1][nt] = __builtin_amdgcn_mfma_f32_16x16x32_bf16(al1, bh, acc[1][nt], 0, 0, 0);
      acc[0][nt] = __builtin_amdgcn_mfma_f32_16x16x32_bf16(ah0, bh, acc[0][nt], 0, 0, 0);
      acc[1][nt] = __builtin_amdgcn_mfma_f32_16x16x32_bf16(ah1, bh, acc[1][nt], 0, 0, 0);
    }
  }

  // ---- epilogue: + pre_src[srcids[m]], store, column stats ----
  float colS[8], colQ[8];
#pragma unroll
  for (int nt = 0; nt < 8; ++nt) { colS[nt] = 0.f; colQ[nt] = 0.f; }
#pragma unroll
  for (int mt = 0; mt < 2; ++mt) {
#pragma unroll
    for (int r = 0; r < 4; ++r) {
      const int m = bm + wave * 32 + mt * 16 + aq * 4 + r;   // C/D: row=quad*4+reg
      const int sid = srcids[m];
      const float* g = pre_src + (size_t)sid * 128;
      float* hp = hpath + (size_t)m * 128;
#pragma unroll
      for (int nt = 0; nt < 8; ++nt) {
        const int col = nt * 16 + am;                        // C/D: col=lane&15
        float v = acc[mt][nt][r] + g[col];
        hp[col] = v;
        colS[nt] += v;
        colQ[nt] += v * v;
      }
    }
  }
#pragma unroll
  for (int nt = 0; nt < 8; ++nt) {
    colS[nt] += __shfl_xor(colS[nt], 16);
    colS[nt] += __shfl_xor(colS[nt], 32);
    colQ[nt] += __shfl_xor(colQ[nt], 16);
    colQ[nt] += __shfl_xor(colQ[nt], 32);
  }
  if (lane < 16) {
#pragma unroll
    for (int nt = 0; nt < 8; ++nt) {
      redS[wave][nt * 16 + lane] = colS[nt];
      redQ[wave][nt * 16 + lane] = colQ[nt];
    }
  }
  __syncthreads();
  if (tid < 128) {
    float s = redS[0][tid] + redS[1][tid] + redS[2][tid] + redS[3][tid];
    atomicAdd(colsum + tid, s);
  } else {
    int cn = tid - 128;
    float s = redQ[0][cn] + redQ[1][cn] + redQ[2][cn] + redQ[3][cn];
    atomicAdd(colsumsq + cn, s);
  }
}

// ---------------------------------------------------------------- fused BN+score+top
// 1024 blocks (4 blocks/CU): per 16-lane group BN coeffs in regs, grid-stride rows,
// per-thread top-6, block merge -> cand
__global__ __launch_bounds__(256)
void k_scoretop(const float* __restrict__ hpath, const float* __restrict__ stP,
                const float* __restrict__ g, const float* __restrict__ b,
                const float* __restrict__ w, KV* __restrict__ cand) {
  const int tid = threadIdx.x;
  const int cg = tid & 15;
  const int grp = (blockIdx.x * 256 + tid) >> 4;   // 0..16383
  float a8[8], c8[8], w8[8];
#pragma unroll
  for (int q = 0; q < 8; ++q) {
    int j = cg * 8 + q;
    float mean = stP[j] * (1.0f / NEDGE);
    float var = stP[128 + j] * (1.0f / NEDGE) - mean * mean;
    float rstd = rsqrtf(var + 1e-5f);
    float aj = g[j] * rstd;
    a8[q] = aj;
    c8[q] = b[j] - aj * mean;
    w8[q] = w[j];
  }
  KV t[TOPN];
#pragma unroll
  for (int q = 0; q < TOPN; ++q) { t[q].v = -INFINITY; t[q].i = 2147483647; }
  for (int row = grp; row < NEDGE; row += 16384) {
    const float* hp = hpath + (size_t)row * 128 + cg * 8;
    const float4 x0 = *(const float4*)hp;
    const float4 x1 = *(const float4*)(hp + 4);
    const float xs[8] = {x0.x, x0.y, x0.z, x0.w, x1.x, x1.y, x1.z, x1.w};
    float part = 0.f;
#pragma unroll
    for (int q = 0; q < 8; ++q)
      part += fmaxf(fmaf(a8[q], xs[q], c8[q]), 0.f) * w8[q];
#pragma unroll
    for (int o = 8; o >= 1; o >>= 1) part += __shfl_xor(part, o, 16);
    if (cg == 0 && part > t[TOPN - 1].v) {
      t[TOPN - 1].v = part;
      t[TOPN - 1].i = row;
#pragma unroll
      for (int q = TOPN - 1; q > 0; --q) {
        if (t[q].v > t[q - 1].v) { KV tmp = t[q - 1]; t[q - 1] = t[q]; t[q] = tmp; }
      }
    }
  }
  __shared__ KV sh[128][TOPN];
  for (int s = 128; s >= 1; s >>= 1) {
    if (tid >= s && tid < 2 * s) {
#pragma unroll
      for (int q = 0; q < TOPN; ++q) sh[tid - s][q] = t[q];
    }
    __syncthreads();
    if (tid < s) kv_merge(t, sh[tid]);
    __syncthreads();
  }
  if (tid == 0) {
#pragma unroll
    for (int q = 0; q < TOPN; ++q) cand[blockIdx.x * TOPN + q] = t[q];
  }
}

__global__ __launch_bounds__(256) void k_top2(const KV* __restrict__ cand,
                                              float* __restrict__ outTail) {
  int tid = threadIdx.x;
  KV t[TOPN];
#pragma unroll
  for (int q = 0; q < TOPN; ++q) t[q] = cand[tid * TOPN + q];
  for (int gset = 1; gset < 4; ++gset) {
    KV o[TOPN];
#pragma unroll
    for (int q = 0; q < TOPN; ++q) o[q] = cand[(gset * 256 + tid) * TOPN + q];
    kv_merge(t, o);
  }
  __shared__ KV sh[128][TOPN];
  for (int s = 128; s >= 1; s >>= 1) {
    if (tid >= s && tid < 2 * s) {
#pragma unroll
      for (int q = 0; q < TOPN; ++q) sh[tid - s][q] = t[q];
    }
    __syncthreads();
    if (tid < s) kv_merge(t, sh[tid]);
    __syncthreads();
  }
  if (tid == 0) {
#pragma unroll
    for (int q = 0; q < TOPN; ++q) {
      outTail[q] = t[q].v;
      outTail[TOPN + q] = (float)t[q].i;
    }
  }
}

// ---------------------------------------------------------------- launch
extern "C" void kernel_launch(void* const* d_in, const int* in_sizes, int n_in,
                              void* d_out, int out_size, void* d_ws, size_t ws_size,
                              hipStream_t stream) {
  const float* paths_srcs = (const float*)d_in[0];
  const float* path_feats = (const float*)d_in[1];
  const int* src_ids = (const int*)d_in[2];
  const float* cew = (const float*)d_in[3];
  const float* ceb = (const float*)d_in[4];
  const float* cw1 = (const float*)d_in[5];
  const float* bng = (const float*)d_in[6];
  const float* bnbt = (const float*)d_in[7];
  const float* cw2 = (const float*)d_in[8];
  const float* l1w = (const float*)d_in[9];
  const float* l1b = (const float*)d_in[10];
  const float* l2w = (const float*)d_in[11];
  const float* l2b = (const float*)d_in[12];
  const float* psw = (const float*)d_in[13];
  const float* psb = (const float*)d_in[14];
  const float* ptw = (const float*)d_in[15];
  const float* ptb = (const float*)d_in[16];
  const float* pbg = (const float*)d_in[17];
  const float* pbb = (const float*)d_in[18];
  const float* scw = (const float*)d_in[19];
  float* out = (float*)d_out;
  float* ws = (float*)d_ws;

  // workspace layout (floats) — unchanged from baseline
  float* w1cat = ws;                        // 49152
  float* wew1cat = w1cat + 49152;           // 90624
  float* bprime = wew1cat + 90624;          // 512
  float* m1 = bprime + 512;                 // 49152
  float* statsT = m1 + 49152;               // 1536 (raw S[384] | raw Q[384] | spare)
  float* statsP = statsT + 1536;            // 512 (raw S[128] | raw Q[128] | spare)
  float* agg = statsP + 512;                // 2360000
  float* T = agg + 2360000;                 // 3840000
  float* H1 = T + 3840000;                  // 1280000
  float* pre_src = H1 + 1280000;            // 1280000
  float* scores_dead = pre_src + 1280000;   // 320000 (hosts cand: 6144 KV = 12288 floats)
  float* candpad = scores_dead + 320000;    // 3072 (legacy cand slot, unused)
  float* hpath = candpad + 3072;            // 40960000
  unsigned short* Bh = (unsigned short*)(hpath + 40960000);  // 32768 ushorts
  unsigned short* Bl = Bh + 32768;                           // 32768 ushorts
  float* bcat = (float*)(Bl + 32768);       // 32768
  float* biascat = bcat + 32768;            // 256
  KV* cand = (KV*)scores_dead;              // 1024 blocks * 6 = 6144 KV
  // CSR arrays overlap the hpath region (dead before hpath is written)
  int* counts = (int*)hpath;                // 10000
  int* offsets = counts + 10000;            // 10001
  int* cursor = offsets + 10001;            // 10000
  int* elist = cursor + 10000;              // 320000
  const size_t needed = (size_t)(49152 + 90624 + 512 + 49152 + 1536 + 512 + 2360000 +
                                 3840000 + 1280000 + 1280000 + 320000 + 3072 +
                                 40960000 + 16384 + 16384 + 32768 + 256) * 4;
  if (ws_size < needed) {
    k_sentinel<<<1, 64, 0, stream>>>(out);
    return;
  }

  // 1. all weight prep + zeroing
  k_prep_all<<<1591, 256, 0, stream>>>(cew, ceb, cw1, cw2, l1w, l2w, psw, l2b, psb, ptb,
                                       ptw, w1cat, wew1cat, bprime, m1, Bh, Bl,
                                       bcat, biascat, statsT, counts);
  // 2-5. CSR build + gather segment-sum
  k_hist<<<(NEDGE + 255) / 256, 256, 0, stream>>>(src_ids, counts);
  k_scan<<<1, 256, 0, stream>>>(counts, offsets, cursor);
  k_scatter<<<(NEDGE + 255) / 256, 256, 0, stream>>>(src_ids, cursor, elist);
  k_gather<<<NSRC, 256, 0, stream>>>(path_feats, offsets, elist, agg);
  // 6. T = ps@W1cat + agg@WeW1cat + bprime, raw stats (64x64 tiles)
  k_gemmT<<<dim3(157, 6), 256, 0, stream>>>(paths_srcs, w1cat, agg, wew1cat, bprime, T,
                                            statsT, statsT + 384);
  // 7. H1 = relu(relu(BN(T))@M1 + l1b)  (BN from raw sums)
  gemm_k<2, 2><<<dim3(157, 2), 256, 0, stream>>>(T, m1, H1, NSRC, 384, 128,
                                                 bng, bnbt, statsT, statsT + 384,
                                                 l1b, nullptr);
  // 8. [node_emb | pre_src] = H1 @ [l2w | l2w@psw] + biascat
  gemm_k<0, 5><<<dim3(157, 4), 256, 0, stream>>>(H1, bcat, out, NSRC, 128, 256,
                                                 nullptr, nullptr, nullptr, nullptr,
                                                 biascat, pre_src);
  // 9. big GEMM (split-bf16 MFMA, async fragment-staged LDS) + gather + stats
  k_hgemm<<<2500, 256, 0, stream>>>(path_feats, Bh, Bl, src_ids, pre_src, hpath,
                                    statsP, statsP + 128);
  // 10-11. fused BN+score+top, then final merge
  k_scoretop<<<1024, 256, 0, stream>>>(hpath, statsP, pbg, pbb, scw, cand);
  k_top2<<<1, 256, 0, stream>>>(cand, out + (size_t)NSRC * 128);
}

// Round 14
// 900.509 us; speedup vs baseline: 1.0188x; 1.0188x over previous
//
#include <hip/hip_runtime.h>
#include <math.h>

#define NSRC 10000
#define NEDGE 320000
#define EDIM 236
#define TOPN 6

typedef __attribute__((ext_vector_type(8))) short short8;
typedef __attribute__((ext_vector_type(4))) float floatx4;

typedef __attribute__((address_space(3))) void lds_void_t;
typedef __attribute__((address_space(1))) const void gmem_void_t;

// async 16B/lane global->LDS: lane l writes lds_base + l*16
__device__ __forceinline__ void g2lds16(const void* g, void* l) {
  __builtin_amdgcn_global_load_lds((gmem_void_t*)g, (lds_void_t*)l, 16, 0, 0);
}

// ---------------------------------------------------------------- bf16 split
__device__ __forceinline__ unsigned short bf16_rne(float x) {
  union { float f; unsigned int u; } c; c.f = x;
  unsigned int r = (c.u + 0x7FFFu + ((c.u >> 16) & 1u)) >> 16;
  return (unsigned short)r;
}
__device__ __forceinline__ float bf16_to_f(unsigned short h) {
  union { unsigned int u; float f; } c; c.u = ((unsigned int)h) << 16;
  return c.f;
}
__device__ __forceinline__ void split_f32(float x, unsigned short& h, unsigned short& l) {
  h = bf16_rne(x);
  l = bf16_rne(x - bf16_to_f(h));
}

// fast split of 8 floats into hi/lo bf16 via v_cvt_pk_bf16_f32 (RNE, bit-identical
// to bf16_rne for normal values)
__device__ __forceinline__ void split8(const float* av, short8& h8, short8& l8) {
  union { short8 s; unsigned int u[4]; } H, L;
#pragma unroll
  for (int p = 0; p < 4; ++p) {
    float x0 = av[2 * p], x1 = av[2 * p + 1];
    unsigned int hp;
    asm("v_cvt_pk_bf16_f32 %0, %1, %2" : "=v"(hp) : "v"(x0), "v"(x1));
    union { unsigned int u; float f; } f0, f1;
    f0.u = hp << 16;
    f1.u = hp & 0xFFFF0000u;
    float l0 = x0 - f0.f, l1 = x1 - f1.f;
    unsigned int lp;
    asm("v_cvt_pk_bf16_f32 %0, %1, %2" : "=v"(lp) : "v"(l0), "v"(l1));
    H.u[p] = hp; L.u[p] = lp;
  }
  h8 = H.s; l8 = L.s;
}

// ---------------------------------------------------------------- top-k utils
struct KV { float v; int i; };

__device__ __forceinline__ bool kv_better(const KV a, const KV b) {
  return (a.v > b.v) || (a.v == b.v && a.i < b.i);
}

__device__ __forceinline__ void kv_merge(KV d[TOPN], const KV o[TOPN]) {
  KV r[TOPN];
  int ia = 0, ib = 0;
#pragma unroll
  for (int q = 0; q < TOPN; ++q) {
    bool takeA;
    if (ia >= TOPN) takeA = false;
    else if (ib >= TOPN) takeA = true;
    else takeA = kv_better(d[ia], o[ib]);
    r[q] = takeA ? d[ia] : o[ib];
    if (takeA) ia++; else ib++;
  }
#pragma unroll
  for (int q = 0; q < TOPN; ++q) d[q] = r[q];
}

__global__ void k_sentinel(float* __restrict__ out) {
  if (threadIdx.x == 0) out[0] = 1.0e9f;
}

// ---------------------------------------------------------------- mega prep
__global__ __launch_bounds__(256)
void k_prep_all(const float* __restrict__ cew, const float* __restrict__ ceb,
                const float* __restrict__ cw1, const float* __restrict__ cw2,
                const float* __restrict__ l1w, const float* __restrict__ l2w,
                const float* __restrict__ psw, const float* __restrict__ l2b,
                const float* __restrict__ psb, const float* __restrict__ ptb,
                const float* __restrict__ ptw,
                float* __restrict__ w1cat, float* __restrict__ wew1cat,
                float* __restrict__ bprime, float* __restrict__ m1,
                unsigned short* __restrict__ Bh, unsigned short* __restrict__ Bl,
                float* __restrict__ bcat, float* __restrict__ biascat,
                float* __restrict__ statsT, int* __restrict__ counts) {
  const int b = blockIdx.x;
  const int tid = threadIdx.x;
  if (b < 708) {                      // wew1cat[k][i*128+j] = sum_m We_i[k][m]*W1_i[m][j]
    if (tid >= 128) return;
    int i = b / EDIM;
    int k = b - i * EDIM;
    const float* we = cew + ((size_t)i * EDIM + k) * 128;
    const float* w1 = cw1 + (size_t)i * 16384;
    float acc = 0.f;
    for (int m = 0; m < 128; ++m) acc = fmaf(we[m], w1[m * 128 + tid], acc);
    wew1cat[k * 384 + i * 128 + tid] = acc;
  } else if (b < 1092) {              // m1[(i*128+r)][j] = sum_c W2_i[r][c]*lin1_W[(i*128+c)][j]
    if (tid >= 128) return;
    int bb = b - 708;
    int i = bb >> 7;
    int r = bb & 127;
    const float* w2 = cw2 + (size_t)i * 16384 + r * 128;
    float acc = 0.f;
    for (int c = 0; c < 128; ++c) acc = fmaf(w2[c], l1w[((size_t)i * 128 + c) * 128 + tid], acc);
    m1[bb * 128 + tid] = acc;
  } else if (b < 1284) {              // w1cat transpose-copy
    int gid = (b - 1092) * 256 + tid;
    if (gid >= 3 * 128 * 128) return;
    int i = gid >> 14;
    int m = (gid >> 7) & 127;
    int j = gid & 127;
    w1cat[m * 384 + i * 128 + j] = cw1[gid];
  } else if (b < 1287) {              // bprime[i*128+j] = sum_m be_i[m]*W1_i[m][j]
    if (tid >= 128) return;
    int i = b - 1284;
    const float* be = ceb + i * 128;
    const float* w1 = cw1 + (size_t)i * 16384;
    float acc = 0.f;
    for (int m = 0; m < 128; ++m) acc = fmaf(be[m], w1[m * 128 + tid], acc);
    bprime[i * 128 + tid] = acc;
  } else if (b < 1415) {              // B split: ptw [236][128] -> Bh/Bl [128][256]
    int n = b - 1287;
    float v = (tid < EDIM) ? ptw[(size_t)tid * 128 + n] : 0.f;
    unsigned short h, l;
    split_f32(v, h, l);
    Bh[n * 256 + tid] = h;
    Bl[n * 256 + tid] = l;
  } else if (b < 1543) {              // bcat [128][256] = [l2w | l2w@psw]; biascat
    if (tid >= 128) return;
    int k = b - 1415;
    bcat[k * 256 + tid] = l2w[k * 128 + tid];
    float acc = 0.f;
    for (int c = 0; c < 128; ++c) acc = fmaf(l2w[k * 128 + c], psw[c * 128 + tid], acc);
    bcat[k * 256 + 128 + tid] = acc;
    if (k == 0) {
      biascat[tid] = l2b[tid];
      float bb = 0.f;
      for (int c = 0; c < 128; ++c) bb = fmaf(l2b[c], psw[c * 128 + tid], bb);
      biascat[128 + tid] = bb + psb[tid] + ptb[tid];
    }
  } else if (b < 1551) {              // zero statsT(1536)+statsP(512)
    int i = (b - 1543) * 256 + tid;
    if (i < 2048) statsT[i] = 0.f;
  } else {                            // zero counts(10000)
    int i = (b - 1551) * 256 + tid;
    if (i < NSRC) counts[i] = 0;
  }
}

// ---------------------------------------------------------------- CSR build
__global__ __launch_bounds__(256) void k_hist(const int* __restrict__ src,
                                              int* __restrict__ counts) {
  int e = blockIdx.x * 256 + threadIdx.x;
  if (e < NEDGE) atomicAdd(&counts[src[e]], 1);
}

__global__ __launch_bounds__(256) void k_scan(const int* __restrict__ counts,
                                              int* __restrict__ offsets,
                                              int* __restrict__ cursor) {
  __shared__ int part[256];
  const int t = threadIdx.x;
  const int base = t * 40;
  int s = 0;
  for (int k = 0; k < 40; ++k) {
    int i = base + k;
    if (i < NSRC) s += counts[i];
  }
  part[t] = s;
  __syncthreads();
  for (int off = 1; off < 256; off <<= 1) {
    int v = (t >= off) ? part[t - off] : 0;
    __syncthreads();
    part[t] += v;
    __syncthreads();
  }
  int run = (t == 0) ? 0 : part[t - 1];
  for (int k = 0; k < 40; ++k) {
    int i = base + k;
    if (i < NSRC) {
      offsets[i] = run;
      cursor[i] = run;
      run += counts[i];
    }
  }
  if (t == 255) offsets[NSRC] = run;
}

__global__ __launch_bounds__(256) void k_scatter(const int* __restrict__ src,
                                                 int* __restrict__ cursor,
                                                 int* __restrict__ elist) {
  int e = blockIdx.x * 256 + threadIdx.x;
  if (e < NEDGE) {
    int p = atomicAdd(&cursor[src[e]], 1);
    elist[p] = e;
  }
}

// agg[row][d] = sum over row's edges of relu(pf[e][d]).
// Wave-per-edge float4 gather (measured neutral vs column version — both HBM-bound
// and coalesced; kept for the cleaner epilogue).
__global__ __launch_bounds__(256) void k_gather(const float* __restrict__ pf,
                                                const int* __restrict__ offsets,
                                                const int* __restrict__ elist,
                                                float* __restrict__ agg) {
  const int row = blockIdx.x;
  const int tid = threadIdx.x;
  const int wave = tid >> 6;
  const int lane = tid & 63;
  __shared__ int sid[64];
  __shared__ float4 red[3][64];
  const int beg = offsets[row];
  const int end = offsets[row + 1];
  float4 a = make_float4(0.f, 0.f, 0.f, 0.f);
  float4 b2 = make_float4(0.f, 0.f, 0.f, 0.f);
  for (int b = beg; b < end; b += 64) {
    const int cnt = min(64, end - b);
    __syncthreads();
    if (tid < cnt) sid[tid] = elist[b + tid];
    __syncthreads();
    if (lane < 59) {
      int e = wave;
      for (; e + 4 < cnt; e += 8) {
        const float* p0 = pf + (size_t)sid[e] * EDIM;
        const float* p1 = pf + (size_t)sid[e + 4] * EDIM;
        const float4 v0 = *(const float4*)(p0 + lane * 4);
        const float4 v1 = *(const float4*)(p1 + lane * 4);
        a.x += fmaxf(v0.x, 0.f); a.y += fmaxf(v0.y, 0.f);
        a.z += fmaxf(v0.z, 0.f); a.w += fmaxf(v0.w, 0.f);
        b2.x += fmaxf(v1.x, 0.f); b2.y += fmaxf(v1.y, 0.f);
        b2.z += fmaxf(v1.z, 0.f); b2.w += fmaxf(v1.w, 0.f);
      }
      if (e < cnt) {
        const float* p0 = pf + (size_t)sid[e] * EDIM;
        const float4 v0 = *(const float4*)(p0 + lane * 4);
        a.x += fmaxf(v0.x, 0.f); a.y += fmaxf(v0.y, 0.f);
        a.z += fmaxf(v0.z, 0.f); a.w += fmaxf(v0.w, 0.f);
      }
    }
  }
  a.x += b2.x; a.y += b2.y; a.z += b2.z; a.w += b2.w;
  __syncthreads();
  if (wave > 0 && lane < 59) red[wave - 1][lane] = a;
  __syncthreads();
  if (wave == 0 && lane < 59) {
    const float4 r0 = red[0][lane];
    const float4 r1 = red[1][lane];
    const float4 r2 = red[2][lane];
    a.x = (a.x + r0.x) + (r1.x + r2.x);
    a.y = (a.y + r0.y) + (r1.y + r2.y);
    a.z = (a.z + r0.z) + (r1.z + r2.z);
    a.w = (a.w + r0.w) + (r1.w + r2.w);
    *(float4*)(agg + (size_t)row * EDIM + lane * 4) = a;
  }
}

// ---------------------------------------------------------------- merged T GEMM (64x64 tiles)
// T[10000,384] = paths_srcs@w1cat + agg@wew1cat + bprime; col sum/sumsq -> statsT
__global__ __launch_bounds__(256)
void k_gemmT(const float* __restrict__ A1, const float* __restrict__ B1,
             const float* __restrict__ A2, const float* __restrict__ B2,
             const float* __restrict__ bias, float* __restrict__ C,
             float* __restrict__ colsum, float* __restrict__ colsumsq) {
  __shared__ float As[8][64];
  __shared__ float Bs[8][64];
  __shared__ float red[16][64];
  const int tid = threadIdx.x;
  const int tx = tid & 15;
  const int ty = tid >> 4;
  const int bm = blockIdx.x * 64;
  const int bn = blockIdx.y * 64;
  const int N = 384;

  float acc[4][4];
#pragma unroll
  for (int i = 0; i < 4; ++i)
#pragma unroll
    for (int j = 0; j < 4; ++j) acc[i][j] = 0.f;

  const int ar = tid & 63;            // A stage row
  const int ac = (tid >> 6) << 1;     // A stage k-pair
  const int bkr = tid >> 5;           // B stage k row
  const int bc = (tid & 31) << 1;     // B stage col pair

#pragma unroll 1
  for (int seg = 0; seg < 2; ++seg) {
    const float* A = seg ? A2 : A1;
    const float* B = seg ? B2 : B1;
    const int K = seg ? EDIM : 128;
    for (int k0 = 0; k0 < K; k0 += 8) {
      {
        float2 v = make_float2(0.f, 0.f);
        int row = bm + ar;
        int k = k0 + ac;
        if (row < NSRC) {
          if (k + 2 <= K) v = *(const float2*)(A + (size_t)row * K + k);
          else if (k < K) v.x = A[(size_t)row * K + k];
        }
        As[ac][ar] = v.x;
        As[ac + 1][ar] = v.y;
      }
      {
        float2 v = make_float2(0.f, 0.f);
        int kk = k0 + bkr;
        if (kk < K) v = *(const float2*)(B + (size_t)kk * N + bn + bc);
        Bs[bkr][bc] = v.x;
        Bs[bkr][bc + 1] = v.y;
      }
      __syncthreads();
#pragma unroll
      for (int kk = 0; kk < 8; ++kk) {
        const float4 a0 = *(const float4*)&As[kk][ty * 4];
        const float4 b0 = *(const float4*)&Bs[kk][tx * 4];
        const float av[4] = {a0.x, a0.y, a0.z, a0.w};
        const float bv[4] = {b0.x, b0.y, b0.z, b0.w};
#pragma unroll
        for (int i = 0; i < 4; ++i)
#pragma unroll
          for (int j = 0; j < 4; ++j) acc[i][j] = fmaf(av[i], bv[j], acc[i][j]);
      }
      __syncthreads();
    }
  }

  const int nb = bn + tx * 4;
  float colS[4], colQ[4];
#pragma unroll
  for (int j = 0; j < 4; ++j) { colS[j] = 0.f; colQ[j] = 0.f; }
#pragma unroll
  for (int i = 0; i < 4; ++i) {
    int m = bm + ty * 4 + i;
    if (m < NSRC) {
      float outv[4];
#pragma unroll
      for (int j = 0; j < 4; ++j) outv[j] = acc[i][j] + bias[nb + j];
      *(float4*)(C + (size_t)m * N + nb) = make_float4(outv[0], outv[1], outv[2], outv[3]);
#pragma unroll
      for (int j = 0; j < 4; ++j) { colS[j] += outv[j]; colQ[j] += outv[j] * outv[j]; }
    }
  }
  *(float4*)&red[ty][tx * 4] = make_float4(colS[0], colS[1], colS[2], colS[3]);
  __syncthreads();
  if (tid < 64) {
    float s = 0.f;
#pragma unroll
    for (int t = 0; t < 16; ++t) s += red[t][tid];
    atomicAdd(colsum + bn + tid, s);
  }
  __syncthreads();
  *(float4*)&red[ty][tx * 4] = make_float4(colQ[0], colQ[1], colQ[2], colQ[3]);
  __syncthreads();
  if (tid < 64) {
    float s = 0.f;
#pragma unroll
    for (int t = 0; t < 16; ++t) s += red[t][tid];
    atomicAdd(colsumsq + bn + tid, s);
  }
}

// ---------------------------------------------------------------- fp32 GEMM (node, 64x64 tiles)
// ATR: 0=none, 2=BN from raw sums + relu on A-load
// EPI: 2=relu(acc+bias); 5=dual-out: col<128 -> C, col>=128 -> C2, both stride 128
template <int ATR, int EPI>
__global__ __launch_bounds__(256)
void gemm_k(const float* __restrict__ A, const float* __restrict__ B,
            float* __restrict__ C, int M, int K, int N,
            const float* __restrict__ bn_g, const float* __restrict__ bn_b,
            const float* __restrict__ rawS, const float* __restrict__ rawQ,
            const float* __restrict__ bias, float* __restrict__ C2) {
  __shared__ float As[8][64];
  __shared__ float Bs[8][64];
  const int tid = threadIdx.x;
  const int tx = tid & 15;
  const int ty = tid >> 4;
  const int bm = blockIdx.x * 64;
  const int bn = blockIdx.y * 64;

  float acc[4][4];
#pragma unroll
  for (int i = 0; i < 4; ++i)
#pragma unroll
    for (int j = 0; j < 4; ++j) acc[i][j] = 0.f;

  const int ar = tid & 63;
  const int ac = (tid >> 6) << 1;
  const int bkr = tid >> 5;
  const int bc = (tid & 31) << 1;

  for (int k0 = 0; k0 < K; k0 += 8) {
    {
      float2 v = make_float2(0.f, 0.f);
      int row = bm + ar;
      int k = k0 + ac;
      if (row < M) {
        if (k + 2 <= K) v = *(const float2*)(A + (size_t)row * K + k);
        else if (k < K) v.x = A[(size_t)row * K + k];
      }
      if constexpr (ATR == 2) {
        float vv[2] = {v.x, v.y};
#pragma unroll
        for (int q = 0; q < 2; ++q) {
          int kk = k0 + ac + q;
          if (kk < K) {
            float mean = rawS[kk] * (1.0f / NSRC);
            float var = rawQ[kk] * (1.0f / NSRC) - mean * mean;
            float rstd = rsqrtf(var + 1e-5f);
            vv[q] = fmaxf(fmaf(bn_g[kk] * rstd, vv[q] - mean, bn_b[kk]), 0.f);
          } else {
            vv[q] = 0.f;
          }
        }
        v = make_float2(vv[0], vv[1]);
      }
      As[ac][ar] = v.x;
      As[ac + 1][ar] = v.y;
    }
    {
      float2 v = make_float2(0.f, 0.f);
      int kk = k0 + bkr;
      if (kk < K) v = *(const float2*)(B + (size_t)kk * N + bn + bc);
      Bs[bkr][bc] = v.x;
      Bs[bkr][bc + 1] = v.y;
    }
    __syncthreads();
#pragma unroll
    for (int kk = 0; kk < 8; ++kk) {
      const float4 a0 = *(const float4*)&As[kk][ty * 4];
      const float4 b0 = *(const float4*)&Bs[kk][tx * 4];
      const float av[4] = {a0.x, a0.y, a0.z, a0.w};
      const float bv[4] = {b0.x, b0.y, b0.z, b0.w};
#pragma unroll
      for (int i = 0; i < 4; ++i)
#pragma unroll
        for (int j = 0; j < 4; ++j) acc[i][j] = fmaf(av[i], bv[j], acc[i][j]);
    }
    __syncthreads();
  }

  const int nb = bn + tx * 4;
#pragma unroll
  for (int i = 0; i < 4; ++i) {
    int m = bm + ty * 4 + i;
    if (m < M) {
      float outv[4];
#pragma unroll
      for (int j = 0; j < 4; ++j) {
        outv[j] = acc[i][j] + bias[nb + j];
        if constexpr (EPI == 2) outv[j] = fmaxf(outv[j], 0.f);
      }
      float* crow;
      if constexpr (EPI == 5) {
        crow = (nb < 128) ? (C + (size_t)m * 128 + nb) : (C2 + (size_t)m * 128 + (nb - 128));
      } else {
        crow = C + (size_t)m * N + nb;
      }
      *(float4*)crow = make_float4(outv[0], outv[1], outv[2], outv[3]);
    }
  }
}

// ---------------------------------------------------------------- big GEMM: split-bf16 MFMA
// hpath[320000,128] = path_feats @ pe_tgt_W + pre_src[srcids[m]]; col sum/sumsq.
// 2-TERM SPLIT: A*B ~= Ah*Bh + Al*Bh (drops the symmetric Ah*Bl cross-term,
// error ~|A||B|*2^-9 per product, ~4e-3 in hpath -- below the pipeline's
// existing atomics-order noise). This removes Bl staging entirely:
// 32 MFMA/chunk (was 48), 2 global_load_lds/wave/chunk (was 4), LDS 20.5 KB
// (was 36.8) -> up to 7 blocks/CU. Same simple 1-barrier dbuf structure that
// measured best (168 us); schedule surgery variants all measured slower.
__global__ __launch_bounds__(256)
void k_hgemm(const float* __restrict__ A, const unsigned short* __restrict__ Bh,
             const unsigned short* __restrict__ Bl, const int* __restrict__ srcids,
             const float* __restrict__ pre_src, float* __restrict__ hpath,
             float* __restrict__ colsum, float* __restrict__ colsumsq) {
  // BF[buf][nt][lane*8 shorts] : each lane's Bh fragment at base + lane*16B
  __shared__ __align__(16) unsigned short BF[2][8][512];
  __shared__ float redS[4][128];
  __shared__ float redQ[4][128];

  const int tid = threadIdx.x;
  const int wave = tid >> 6;
  const int lane = tid & 63;
  const int am = lane & 15;
  const int aq = lane >> 4;
  const int bm = blockIdx.x * 128;

  floatx4 acc[2][8];
#pragma unroll
  for (int mt = 0; mt < 2; ++mt)
#pragma unroll
    for (int nt = 0; nt < 8; ++nt) acc[mt][nt] = (floatx4){0.f, 0.f, 0.f, 0.f};

  const float* a0p = A + (size_t)(bm + wave * 32 + am) * EDIM;   // 16B-aligned (944=59*16)
  const float* a1p = a0p + 16 * EDIM;

  // staging: wave w owns nt = {2w, 2w+1}; per-lane src = fragment (nt, lane)
  const int nt0 = wave * 2, nt1 = nt0 + 1;
  const unsigned short* sH0 = Bh + (size_t)(nt0 * 16 + am) * 256 + aq * 8;
  const unsigned short* sH1 = Bh + (size_t)(nt1 * 16 + am) * 256 + aq * 8;
  (void)Bl;  // low half of B unused in 2-term split

  auto stage = [&](int c, int buf) {
    g2lds16(sH0 + c * 32, &BF[buf][nt0][0]);
    g2lds16(sH1 + c * 32, &BF[buf][nt1][0]);
  };

  float pA0[8], pA1[8];
  auto loadA = [&](int c) {
    const int kA = c * 32 + aq * 8;
    if (kA + 8 <= EDIM) {
      float4 x = *(const float4*)(a0p + kA);
      float4 y = *(const float4*)(a0p + kA + 4);
      pA0[0] = x.x; pA0[1] = x.y; pA0[2] = x.z; pA0[3] = x.w;
      pA0[4] = y.x; pA0[5] = y.y; pA0[6] = y.z; pA0[7] = y.w;
      x = *(const float4*)(a1p + kA);
      y = *(const float4*)(a1p + kA + 4);
      pA1[0] = x.x; pA1[1] = x.y; pA1[2] = x.z; pA1[3] = x.w;
      pA1[4] = y.x; pA1[5] = y.y; pA1[6] = y.z; pA1[7] = y.w;
    } else {
#pragma unroll
      for (int q = 0; q < 8; ++q) {
        int k = kA + q;
        pA0[q] = (k < EDIM) ? a0p[k] : 0.f;
        pA1[q] = (k < EDIM) ? a1p[k] : 0.f;
      }
    }
  };

  stage(0, 0);
  loadA(0);
#pragma unroll 1
  for (int c = 0; c < 8; ++c) {
    // split current A (covers in-flight loads with VALU)
    short8 ah0, al0, ah1, al1;
    split8(pA0, ah0, al0);
    split8(pA1, ah1, al1);
    __syncthreads();                 // drains vmcnt: BF[c&1] ready for all waves
    if (c < 7) {
      stage(c + 1, (c + 1) & 1);     // async B for next chunk (other buffer)
      loadA(c + 1);                  // A loads land during MFMA below
    }
    const int buf = c & 1;
#pragma unroll
    for (int nt = 0; nt < 8; ++nt) {
      const short8 bh = *(const short8*)&BF[buf][nt][lane * 8];
      acc[0][nt] = __builtin_amdgcn_mfma_f32_16x16x32_bf16(al0, bh, acc[0][nt], 0, 0, 0);
      acc[1][nt] = __builtin_amdgcn_mfma_f32_16x16x32_bf16(al1, bh, acc[1][nt], 0, 0, 0);
      acc[0][nt] = __builtin_amdgcn_mfma_f32_16x16x32_bf16(ah0, bh, acc[0][nt], 0, 0, 0);
      acc[1][nt] = __builtin_amdgcn_mfma_f32_16x16x32_bf16(ah1, bh, acc[1][nt], 0, 0, 0);
    }
  }

  // ---- epilogue: + pre_src[srcids[m]], store, column stats ----
  float colS[8], colQ[8];
#pragma unroll
  for (int nt = 0; nt < 8; ++nt) { colS[nt] = 0.f; colQ[nt] = 0.f; }
#pragma unroll
  for (int mt = 0; mt < 2; ++mt) {
#pragma unroll
    for (int r = 0; r < 4; ++r) {
      const int m = bm + wave * 32 + mt * 16 + aq * 4 + r;   // C/D: row=quad*4+reg
      const int sid = srcids[m];
      const float* g = pre_src + (size_t)sid * 128;
      float* hp = hpath + (size_t)m * 128;
#pragma unroll
      for (int nt = 0; nt < 8; ++nt) {
        const int col = nt * 16 + am;                        // C/D: col=lane&15
        float v = acc[mt][nt][r] + g[col];
        hp[col] = v;
        colS[nt] += v;
        colQ[nt] += v * v;
      }
    }
  }
#pragma unroll
  for (int nt = 0; nt < 8; ++nt) {
    colS[nt] += __shfl_xor(colS[nt], 16);
    colS[nt] += __shfl_xor(colS[nt], 32);
    colQ[nt] += __shfl_xor(colQ[nt], 16);
    colQ[nt] += __shfl_xor(colQ[nt], 32);
  }
  if (lane < 16) {
#pragma unroll
    for (int nt = 0; nt < 8; ++nt) {
      redS[wave][nt * 16 + lane] = colS[nt];
      redQ[wave][nt * 16 + lane] = colQ[nt];
    }
  }
  __syncthreads();
  if (tid < 128) {
    float s = redS[0][tid] + redS[1][tid] + redS[2][tid] + redS[3][tid];
    atomicAdd(colsum + tid, s);
  } else {
    int cn = tid - 128;
    float s = redQ[0][cn] + redQ[1][cn] + redQ[2][cn] + redQ[3][cn];
    atomicAdd(colsumsq + cn, s);
  }
}

// ---------------------------------------------------------------- fused BN+score+top
// 1024 blocks (4 blocks/CU): per 16-lane group BN coeffs in regs, grid-stride rows,
// per-thread top-6, block merge -> cand
__global__ __launch_bounds__(256)
void k_scoretop(const float* __restrict__ hpath, const float* __restrict__ stP,
                const float* __restrict__ g, const float* __restrict__ b,
                const float* __restrict__ w, KV* __restrict__ cand) {
  const int tid = threadIdx.x;
  const int cg = tid & 15;
  const int grp = (blockIdx.x * 256 + tid) >> 4;   // 0..16383
  float a8[8], c8[8], w8[8];
#pragma unroll
  for (int q = 0; q < 8; ++q) {
    int j = cg * 8 + q;
    float mean = stP[j] * (1.0f / NEDGE);
    float var = stP[128 + j] * (1.0f / NEDGE) - mean * mean;
    float rstd = rsqrtf(var + 1e-5f);
    float aj = g[j] * rstd;
    a8[q] = aj;
    c8[q] = b[j] - aj * mean;
    w8[q] = w[j];
  }
  KV t[TOPN];
#pragma unroll
  for (int q = 0; q < TOPN; ++q) { t[q].v = -INFINITY; t[q].i = 2147483647; }
  for (int row = grp; row < NEDGE; row += 16384) {
    const float* hp = hpath + (size_t)row * 128 + cg * 8;
    const float4 x0 = *(const float4*)hp;
    const float4 x1 = *(const float4*)(hp + 4);
    const float xs[8] = {x0.x, x0.y, x0.z, x0.w, x1.x, x1.y, x1.z, x1.w};
    float part = 0.f;
#pragma unroll
    for (int q = 0; q < 8; ++q)
      part += fmaxf(fmaf(a8[q], xs[q], c8[q]), 0.f) * w8[q];
#pragma unroll
    for (int o = 8; o >= 1; o >>= 1) part += __shfl_xor(part, o, 16);
    if (cg == 0 && part > t[TOPN - 1].v) {
      t[TOPN - 1].v = part;
      t[TOPN - 1].i = row;
#pragma unroll
      for (int q = TOPN - 1; q > 0; --q) {
        if (t[q].v > t[q - 1].v) { KV tmp = t[q - 1]; t[q - 1] = t[q]; t[q] = tmp; }
      }
    }
  }
  __shared__ KV sh[128][TOPN];
  for (int s = 128; s >= 1; s >>= 1) {
    if (tid >= s && tid < 2 * s) {
#pragma unroll
      for (int q = 0; q < TOPN; ++q) sh[tid - s][q] = t[q];
    }
    __syncthreads();
    if (tid < s) kv_merge(t, sh[tid]);
    __syncthreads();
  }
  if (tid == 0) {
#pragma unroll
    for (int q = 0; q < TOPN; ++q) cand[blockIdx.x * TOPN + q] = t[q];
  }
}

__global__ __launch_bounds__(256) void k_top2(const KV* __restrict__ cand,
                                              float* __restrict__ outTail) {
  int tid = threadIdx.x;
  KV t[TOPN];
#pragma unroll
  for (int q = 0; q < TOPN; ++q) t[q] = cand[tid * TOPN + q];
  for (int gset = 1; gset < 4; ++gset) {
    KV o[TOPN];
#pragma unroll
    for (int q = 0; q < TOPN; ++q) o[q] = cand[(gset * 256 + tid) * TOPN + q];
    kv_merge(t, o);
  }
  __shared__ KV sh[128][TOPN];
  for (int s = 128; s >= 1; s >>= 1) {
    if (tid >= s && tid < 2 * s) {
#pragma unroll
      for (int q = 0; q < TOPN; ++q) sh[tid - s][q] = t[q];
    }
    __syncthreads();
    if (tid < s) kv_merge(t, sh[tid]);
    __syncthreads();
  }
  if (tid == 0) {
#pragma unroll
    for (int q = 0; q < TOPN; ++q) {
      outTail[q] = t[q].v;
      outTail[TOPN + q] = (float)t[q].i;
    }
  }
}

// ---------------------------------------------------------------- launch
extern "C" void kernel_launch(void* const* d_in, const int* in_sizes, int n_in,
                              void* d_out, int out_size, void* d_ws, size_t ws_size,
                              hipStream_t stream) {
  const float* paths_srcs = (const float*)d_in[0];
  const float* path_feats = (const float*)d_in[1];
  const int* src_ids = (const int*)d_in[2];
  const float* cew = (const float*)d_in[3];
  const float* ceb = (const float*)d_in[4];
  const float* cw1 = (const float*)d_in[5];
  const float* bng = (const float*)d_in[6];
  const float* bnbt = (const float*)d_in[7];
  const float* cw2 = (const float*)d_in[8];
  const float* l1w = (const float*)d_in[9];
  const float* l1b = (const float*)d_in[10];
  const float* l2w = (const float*)d_in[11];
  const float* l2b = (const float*)d_in[12];
  const float* psw = (const float*)d_in[13];
  const float* psb = (const float*)d_in[14];
  const float* ptw = (const float*)d_in[15];
  const float* ptb = (const float*)d_in[16];
  const float* pbg = (const float*)d_in[17];
  const float* pbb = (const float*)d_in[18];
  const float* scw = (const float*)d_in[19];
  float* out = (float*)d_out;
  float* ws = (float*)d_ws;

  // workspace layout (floats) — unchanged from baseline
  float* w1cat = ws;                        // 49152
  float* wew1cat = w1cat + 49152;           // 90624
  float* bprime = wew1cat + 90624;          // 512
  float* m1 = bprime + 512;                 // 49152
  float* statsT = m1 + 49152;               // 1536 (raw S[384] | raw Q[384] | spare)
  float* statsP = statsT + 1536;            // 512 (raw S[128] | raw Q[128] | spare)
  float* agg = statsP + 512;                // 2360000
  float* T = agg + 2360000;                 // 3840000
  float* H1 = T + 3840000;                  // 1280000
  float* pre_src = H1 + 1280000;            // 1280000
  float* scores_dead = pre_src + 1280000;   // 320000 (hosts cand: 6144 KV = 12288 floats)
  float* candpad = scores_dead + 320000;    // 3072 (legacy cand slot, unused)
  float* hpath = candpad + 3072;            // 40960000
  unsigned short* Bh = (unsigned short*)(hpath + 40960000);  // 32768 ushorts
  unsigned short* Bl = Bh + 32768;                           // 32768 ushorts
  float* bcat = (float*)(Bl + 32768);       // 32768
  float* biascat = bcat + 32768;            // 256
  KV* cand = (KV*)scores_dead;              // 1024 blocks * 6 = 6144 KV
  // CSR arrays overlap the hpath region (dead before hpath is written)
  int* counts = (int*)hpath;                // 10000
  int* offsets = counts + 10000;            // 10001
  int* cursor = offsets + 10001;            // 10000
  int* elist = cursor + 10000;              // 320000
  const size_t needed = (size_t)(49152 + 90624 + 512 + 49152 + 1536 + 512 + 2360000 +
                                 3840000 + 1280000 + 1280000 + 320000 + 3072 +
                                 40960000 + 16384 + 16384 + 32768 + 256) * 4;
  if (ws_size < needed) {
    k_sentinel<<<1, 64, 0, stream>>>(out);
    return;
  }

  // 1. all weight prep + zeroing
  k_prep_all<<<1591, 256, 0, stream>>>(cew, ceb, cw1, cw2, l1w, l2w, psw, l2b, psb, ptb,
                                       ptw, w1cat, wew1cat, bprime, m1, Bh, Bl,
                                       bcat, biascat, statsT, counts);
  // 2-5. CSR build + gather segment-sum
  k_hist<<<(NEDGE + 255) / 256, 256, 0, stream>>>(src_ids, counts);
  k_scan<<<1, 256, 0, stream>>>(counts, offsets, cursor);
  k_scatter<<<(NEDGE + 255) / 256, 256, 0, stream>>>(src_ids, cursor, elist);
  k_gather<<<NSRC, 256, 0, stream>>>(path_feats, offsets, elist, agg);
  // 6. T = ps@W1cat + agg@WeW1cat + bprime, raw stats (64x64 tiles)
  k_gemmT<<<dim3(157, 6), 256, 0, stream>>>(paths_srcs, w1cat, agg, wew1cat, bprime, T,
                                            statsT, statsT + 384);
  // 7. H1 = relu(relu(BN(T))@M1 + l1b)  (BN from raw sums)
  gemm_k<2, 2><<<dim3(157, 2), 256, 0, stream>>>(T, m1, H1, NSRC, 384, 128,
                                                 bng, bnbt, statsT, statsT + 384,
                                                 l1b, nullptr);
  // 8. [node_emb | pre_src] = H1 @ [l2w | l2w@psw] + biascat
  gemm_k<0, 5><<<dim3(157, 4), 256, 0, stream>>>(H1, bcat, out, NSRC, 128, 256,
                                                 nullptr, nullptr, nullptr, nullptr,
                                                 biascat, pre_src);
  // 9. big GEMM (2-term split-bf16 MFMA, async fragment-staged LDS) + gather + stats
  k_hgemm<<<2500, 256, 0, stream>>>(path_feats, Bh, Bl, src_ids, pre_src, hpath,
                                    statsP, statsP + 128);
  // 10-11. fused BN+score+top, then final merge
  k_scoretop<<<1024, 256, 0, stream>>>(hpath, statsP, pbg, pbb, scw, cand);
  k_top2<<<1, 256, 0, stream>>>(cand, out + (size_t)NSRC * 128);
}